// Round 8
// baseline (44199.310 us; speedup 1.0000x reference)
//
#include <hip/hip_runtime.h>
#include <math.h>

// EncoderDecoder LSTM seq2seq, f32 throughout.
// v6: v2-r3 skeleton (16.8ms proven: load->bar->store->bar->compute, fused
// argmax via pval/pidx, no atomics, no min-waves cap) + enlarged tiles with
// hand-verified bank maps (<=8 addrs/bank-quad for b128, <=2/bank for b32).
// Cell 4bx4r: wave = ks(32)xrp(2), bq uniform; swizzle lq(q,key) spreads the
// kq=2ks+q progression over all 8 quads. Logits 4bx8v, 128 v/block, grid 250.
// Split-K partials use rotation cols ((b+ks)&31 cell; +5*b logits, 5 coprime
// 32) -- v5's part writes hit 1 bank; v5's atomicMax hotspot removed.

#define BB   32
#define SEQ  128
#define HID  1024
#define NV   32000
#define TDEC 64
#define NPRT 250

typedef float f32x4_t __attribute__((ext_vector_type(4)));

__device__ __forceinline__ float sgm(float x) { return 1.0f / (1.0f + expf(-x)); }
__device__ __forceinline__ float dot4(float4 a, float4 b) {
    return a.x*b.x + a.y*b.y + a.z*b.z + a.w*b.w;
}
// LDS quad swizzle: global quad q of a row stored at LDS quad lq(q,row).
// Involutive per 8-quad block (high bits unchanged); mixes q>>3 into the
// bank-quad bits so strided progressions (q=2ks+q0, q=8ks+q0) spread evenly.
__device__ __forceinline__ int lq(int q, int key) {
    return (q & ~7) | ((q ^ (q >> 3) ^ key) & 7);
}

// ---------------------------------------------------------------------------
// Fused LSTM cell. grid = 512 (2 hidden cols -> 8 gate-rows), block = 512.
// tid = ks + 32*rp + 64*bq: ks 32-way K-split (2 quads/chunk), rp 2 (4 rows),
// bq 8 = wave id (4 b's). Per kq: 4 a-reads + 4 w-reads -> 64 FMA.
// Row r (0..7) <-> global W row j0 + (r&1) + (r>>1)*HID.
// ---------------------------------------------------------------------------
template <int XK>
__global__ void __launch_bounds__(512) lstm_cell(
    const float* __restrict__ xdir,   // [BB][XK] or nullptr
    const float* __restrict__ emb,    // [V][XK] or nullptr
    const int*   __restrict__ x, int xoff,   // encoder token path
    const int*   __restrict__ tok,           // decoder t=0 path
    const float* __restrict__ pval,          // fused-argmax path (decoder t>0)
    const int*   __restrict__ pidx,
    const float* __restrict__ Wih,    // [4H][XK]
    const float* __restrict__ Whh,    // [4H][H]
    const float* __restrict__ bias,   // [4H]
    const float* __restrict__ h_in,   // [BB][H]
    float*       __restrict__ h_out,  // [BB][H]
    float*       __restrict__ c_st)   // [BB][H] in/out
{
    constexpr int NCH = (XK + HID) / 256;

    __shared__ float Ach[32 * 256];   // 32KB; part[32][8][32] aliases after compute
    __shared__ float Wch[8 * 256];    // 8KB;  gs[8][32] aliases after part
    __shared__ int   tokl[32];
    __shared__ float pvr[512];
    __shared__ int   pir[512];
    float* part = Ach;
    float* gs   = Wch;

    const int tid = threadIdx.x;
    const int ks  = tid & 31;
    const int rp  = (tid >> 5) & 1;
    const int bq  = tid >> 6;
    const int j0  = blockIdx.x * 2;

    // ---- resolve embedding row indices ----
    if (emb) {
        if (pval) {
            const int b = tid & 31, pg = tid >> 5;
            float bv = -3.402823e38f; int bi = 0x7fffffff;
            for (int p = pg; p < NPRT; p += 16) {
                const float v = pval[p * 32 + b];
                const int  ix = pidx[p * 32 + b];
                if (v > bv || (v == bv && ix < bi)) { bv = v; bi = ix; }
            }
            pvr[pg * 32 + b] = bv; pir[pg * 32 + b] = bi;
            __syncthreads();
            if (tid < 32) {
                float v0 = pvr[tid]; int i0 = pir[tid];
                #pragma unroll
                for (int g = 1; g < 16; ++g) {
                    const float v = pvr[g * 32 + tid];
                    const int  ix = pir[g * 32 + tid];
                    if (v > v0 || (v == v0 && ix < i0)) { v0 = v; i0 = ix; }
                }
                tokl[tid] = i0;
            }
            __syncthreads();
        } else if (x) {
            if (tid < 32) tokl[tid] = x[tid * SEQ + xoff];
            __syncthreads();
        } else {
            if (tid < 32) tokl[tid] = tok[tid];
            __syncthreads();
        }
    }

    // ---- staging coords (global linear/coalesced; LDS write swizzled) ----
    const int ar = tid >> 4, al = tid & 15;      // A: row 0..31, quads al+16i
    const int wr = tid >> 6, wl = tid & 63;      // W: row 0..7 (wave-uniform)
    const int wrow_g = j0 + (wr & 1) + (wr >> 1) * HID;

    const float* arowx = emb ? (emb + (size_t)tokl[ar] * XK)
                             : (xdir + (size_t)ar * XK);
    const float* arowh = h_in + (size_t)ar * HID;

    float acc[4][4];
    #pragma unroll
    for (int p = 0; p < 4; ++p)
        #pragma unroll
        for (int i = 0; i < 4; ++i) acc[p][i] = 0.0f;

    for (int ch = 0; ch < NCH; ++ch) {
        const int kb = ch * 256;   // chunk never straddles the XK boundary

        const float* as = (kb < XK) ? (arowx + kb) : (arowh + (kb - XK));
        float4 aR[4];
        #pragma unroll
        for (int i2 = 0; i2 < 4; ++i2)
            aR[i2] = *reinterpret_cast<const float4*>(as + 4 * (al + 16 * i2));
        const float* wsp = (kb < XK) ? (Wih + (size_t)wrow_g * XK + kb)
                                     : (Whh + (size_t)wrow_g * HID + (kb - XK));
        const float4 wv = *reinterpret_cast<const float4*>(wsp + wl * 4);

        __syncthreads();   // previous chunk's readers done
        #pragma unroll
        for (int i2 = 0; i2 < 4; ++i2)
            *reinterpret_cast<float4*>(&Ach[ar * 256 + 4 * lq(al + 16 * i2, ar)]) = aR[i2];
        *reinterpret_cast<float4*>(&Wch[wr * 256 + 4 * lq(wl, wr)]) = wv;
        __syncthreads();

        #pragma unroll
        for (int q = 0; q < 2; ++q) {
            const int kq = ks * 2 + q;
            float4 av[4], wf[4];
            #pragma unroll
            for (int i = 0; i < 4; ++i) {
                const int brow = bq * 4 + i;
                av[i] = *reinterpret_cast<const float4*>(&Ach[brow * 256 + 4 * lq(kq, brow)]);
            }
            #pragma unroll
            for (int p = 0; p < 4; ++p) {
                const int r = rp * 4 + p;
                wf[p] = *reinterpret_cast<const float4*>(&Wch[r * 256 + 4 * lq(kq, r)]);
            }
            #pragma unroll
            for (int p = 0; p < 4; ++p)
                #pragma unroll
                for (int i = 0; i < 4; ++i)
                    acc[p][i] += dot4(av[i], wf[p]);
        }
    }

    // ---- split-K partials (alias Ach; rotation (b+ks)&31: 2 addrs/bank) ----
    __syncthreads();
    #pragma unroll
    for (int p = 0; p < 4; ++p)
        #pragma unroll
        for (int i = 0; i < 4; ++i)
            part[(ks * 8 + rp * 4 + p) * 32 + ((bq * 4 + i + ks) & 31)] = acc[p][i];
    __syncthreads();

    if (tid < 256) {
        const int r2 = tid >> 5, b2 = tid & 31;
        float s = 0.0f;
        #pragma unroll
        for (int k2 = 0; k2 < 32; ++k2)
            s += part[(k2 * 8 + r2) * 32 + ((b2 + k2) & 31)];
        gs[r2 * 32 + b2] = s;
    }
    __syncthreads();

    if (tid < 64) {
        const int b = tid & 31, jl = tid >> 5;
        const int j = j0 + jl;
        float g4[4];
        #pragma unroll
        for (int g = 0; g < 4; ++g)
            g4[g] = gs[(g * 2 + jl) * 32 + b] + bias[j + g * HID];
        const float cp = c_st[b * HID + j];
        const float cn = sgm(g4[1]) * cp + sgm(g4[0]) * tanhf(g4[2]);
        const float hn = sgm(g4[3]) * tanhf(cn);
        c_st[b * HID + j]  = cn;
        h_out[b * HID + j] = hn;
    }
}

// ---------------------------------------------------------------------------
// Logits + per-block argmax partials. grid = 250 (128 v each), block = 512.
// tid = ks + 4*bq + 32*vg: ks 4-way K-split, bq 8 (4 b's), vg 16 (8 v's).
// Per kq: 4 a-reads (spread, free) + 8 w-reads (broadcast) -> 128 FMA.
// ---------------------------------------------------------------------------
__global__ void __launch_bounds__(512) logits_kernel(
    const float* __restrict__ h1,    // [BB][H]
    const float* __restrict__ W,     // [V][H]
    const float* __restrict__ bias,  // [V]
    float*       __restrict__ out,   // [BB][TDEC][1][V]
    int t,
    float*       __restrict__ pval,  // [250][BB]
    int*         __restrict__ pidx)  // [250][BB]
{
    __shared__ float Wch[128 * 128]; // 64KB; part[4][32][128] aliases after compute
    __shared__ float Ach[32 * 128];  // 16KB
    __shared__ float rv[16 * 32];
    __shared__ int   ri[16 * 32];
    float* part = Wch;

    const int tid = threadIdx.x;
    const int ks  = tid & 3;
    const int bq  = (tid >> 2) & 7;
    const int vg  = tid >> 5;        // 0..15
    const int v0  = blockIdx.x * 128;

    // staging coords
    const int sro = tid >> 5, scq = tid & 31;   // rows sro+16i, 32 quads/row

    float acc[4][8];
    #pragma unroll
    for (int i = 0; i < 4; ++i)
        #pragma unroll
        for (int p = 0; p < 8; ++p) acc[i][p] = 0.0f;

    for (int ch = 0; ch < 8; ++ch) {
        const int k0 = ch * 128;

        float4 wR[8], aR[2];
        #pragma unroll
        for (int i = 0; i < 8; ++i)
            wR[i] = *reinterpret_cast<const float4*>(
                W + (size_t)(v0 + sro + 16 * i) * HID + k0 + scq * 4);
        #pragma unroll
        for (int i = 0; i < 2; ++i)
            aR[i] = *reinterpret_cast<const float4*>(
                h1 + (size_t)(sro + 16 * i) * HID + k0 + scq * 4);

        __syncthreads();
        #pragma unroll
        for (int i = 0; i < 8; ++i) {
            const int row = sro + 16 * i;
            *reinterpret_cast<float4*>(&Wch[row * 128 + 4 * lq(scq, row)]) = wR[i];
        }
        #pragma unroll
        for (int i = 0; i < 2; ++i) {
            const int row = sro + 16 * i;
            *reinterpret_cast<float4*>(&Ach[row * 128 + 4 * lq(scq, row)]) = aR[i];
        }
        __syncthreads();

        #pragma unroll
        for (int q = 0; q < 8; ++q) {
            const int kq = ks * 8 + q;
            float4 av[4], wf[8];
            #pragma unroll
            for (int i = 0; i < 4; ++i) {
                const int brow = bq * 4 + i;
                av[i] = *reinterpret_cast<const float4*>(&Ach[brow * 128 + 4 * lq(kq, brow)]);
            }
            #pragma unroll
            for (int p = 0; p < 8; ++p) {
                const int vr = vg * 8 + p;
                wf[p] = *reinterpret_cast<const float4*>(&Wch[vr * 128 + 4 * lq(kq, vr)]);
            }
            #pragma unroll
            for (int i = 0; i < 4; ++i)
                #pragma unroll
                for (int p = 0; p < 8; ++p)
                    acc[i][p] += dot4(av[i], wf[p]);
        }
    }

    // ---- split-K partials (alias Wch; col rotation *5 is coprime to 32) ----
    __syncthreads();
    #pragma unroll
    for (int i = 0; i < 4; ++i)
        #pragma unroll
        for (int p = 0; p < 8; ++p) {
            const int b = bq * 4 + i, vr = vg * 8 + p;
            part[ks * 4096 + b * 128 + ((vr + 5 * b) & 127)] = acc[i][p];
        }
    __syncthreads();

    // reduce: thread (b, vv) handles 8 v; bias, out store, per-thread argmax
    {
        const int b  = tid & 31;
        const int vv = tid >> 5;     // 0..15
        float res[8];
        float bestv = -3.402823e38f;
        int   besti = 0;
        #pragma unroll
        for (int m = 0; m < 8; ++m) {
            const int vr = vv * 8 + m;
            const int col = (vr + 5 * b) & 127;
            float s = part[0 * 4096 + b * 128 + col] + part[1 * 4096 + b * 128 + col]
                    + part[2 * 4096 + b * 128 + col] + part[3 * 4096 + b * 128 + col];
            res[m] = s + bias[v0 + vr];
            if (res[m] > bestv) { bestv = res[m]; besti = v0 + vr; }
        }
        const size_t ob = ((size_t)b * TDEC + t) * (size_t)NV + v0 + vv * 8;
        f32x4_t n0, n1;
        n0.x = res[0]; n0.y = res[1]; n0.z = res[2]; n0.w = res[3];
        n1.x = res[4]; n1.y = res[5]; n1.z = res[6]; n1.w = res[7];
        __builtin_nontemporal_store(n0, reinterpret_cast<f32x4_t*>(&out[ob]));
        __builtin_nontemporal_store(n1, reinterpret_cast<f32x4_t*>(&out[ob + 4]));
        rv[vv * 32 + b] = bestv;
        ri[vv * 32 + b] = besti;
    }
    __syncthreads();
    if (tid < 32) {
        const int b = tid;
        float bv = rv[b];
        int   bi = ri[b];
        #pragma unroll
        for (int g = 1; g < 16; ++g) {
            const float v = rv[g * 32 + b];
            const int  ix = ri[g * 32 + b];
            if (v > bv || (v == bv && ix < bi)) { bv = v; bi = ix; }
        }
        pval[(size_t)blockIdx.x * BB + b] = bv;
        pidx[(size_t)blockIdx.x * BB + b] = bi;
    }
}

__global__ void __launch_bounds__(256) init_state(
    float* h0, float* c0, float* h1, float* c1, int* tok)
{
    const int i = blockIdx.x * 256 + threadIdx.x;
    if (i < BB * HID) { h0[i] = 0.f; c0[i] = 0.f; h1[i] = 0.f; c1[i] = 0.f; }
    if (i < BB) tok[i] = 1;  // BOS
}

// ---------------------------------------------------------------------------
extern "C" void kernel_launch(void* const* d_in, const int* in_sizes, int n_in,
                              void* d_out, int out_size, void* d_ws, size_t ws_size,
                              hipStream_t stream)
{
    const int*   x       = (const int*)  d_in[0];
    const float* enc_emb = (const float*)d_in[1];
    const float* dec_emb = (const float*)d_in[2];
    const float* eWih0   = (const float*)d_in[3];
    const float* eWhh0   = (const float*)d_in[4];
    const float* eb0     = (const float*)d_in[5];
    const float* eWih1   = (const float*)d_in[6];
    const float* eWhh1   = (const float*)d_in[7];
    const float* eb1     = (const float*)d_in[8];
    const float* dWih0   = (const float*)d_in[9];
    const float* dWhh0   = (const float*)d_in[10];
    const float* db0     = (const float*)d_in[11];
    const float* dWih1   = (const float*)d_in[12];
    const float* dWhh1   = (const float*)d_in[13];
    const float* db1     = (const float*)d_in[14];
    const float* pW      = (const float*)d_in[15];
    const float* pb      = (const float*)d_in[16];
    float* out = (float*)d_out;

    // workspace layout (floats)
    float* w = (float*)d_ws;
    float* h0buf[2] = { w, w + 32768 };
    float* c0       = w + 65536;
    float* h1buf[2] = { w + 98304, w + 131072 };
    float* c1       = w + 163840;
    int*   tok      = (int*)(w + 196608);
    float* pval     = w + 196608 + 64;
    int*   pidx     = (int*)(w + 196608 + 64 + 8000);

    init_state<<<dim3(128), dim3(256), 0, stream>>>(h0buf[0], c0, h1buf[0], c1, tok);

    int cur0 = 0, cur1 = 0;

    // ---- encoder: 128 steps x 2 layers ----
    for (int t = 0; t < SEQ; ++t) {
        lstm_cell<512><<<dim3(512), dim3(512), 0, stream>>>(
            nullptr, enc_emb, x, t, nullptr, nullptr, nullptr,
            eWih0, eWhh0, eb0, h0buf[cur0], h0buf[cur0 ^ 1], c0);
        cur0 ^= 1;
        lstm_cell<1024><<<dim3(512), dim3(512), 0, stream>>>(
            h0buf[cur0], nullptr, nullptr, 0, nullptr, nullptr, nullptr,
            eWih1, eWhh1, eb1, h1buf[cur1], h1buf[cur1 ^ 1], c1);
        cur1 ^= 1;
    }

    // ---- decoder: 64 greedy steps (argmax fused into cell0) ----
    for (int t = 0; t < TDEC; ++t) {
        if (t == 0) {
            lstm_cell<1024><<<dim3(512), dim3(512), 0, stream>>>(
                nullptr, dec_emb, nullptr, 0, tok, nullptr, nullptr,
                dWih0, dWhh0, db0, h0buf[cur0], h0buf[cur0 ^ 1], c0);
        } else {
            lstm_cell<1024><<<dim3(512), dim3(512), 0, stream>>>(
                nullptr, dec_emb, nullptr, 0, nullptr, pval, pidx,
                dWih0, dWhh0, db0, h0buf[cur0], h0buf[cur0 ^ 1], c0);
        }
        cur0 ^= 1;
        lstm_cell<1024><<<dim3(512), dim3(512), 0, stream>>>(
            h0buf[cur0], nullptr, nullptr, 0, nullptr, nullptr, nullptr,
            dWih1, dWhh1, db1, h1buf[cur1], h1buf[cur1 ^ 1], c1);
        cur1 ^= 1;
        logits_kernel<<<dim3(250), dim3(512), 0, stream>>>(
            h1buf[cur1], pW, pb, out, t, pval, pidx);
    }
}